// Round 7
// baseline (497.010 us; speedup 1.0000x reference)
//
#include <hip/hip_runtime.h>

constexpr int TPB  = 256;
constexpr int TPBW = 1024;             // wide blocks: 64 KB LDS, 2 blocks/CU max
constexpr int CBITS = 17;              // 131072 nibble bins per chunk in 64 KB LDS
constexpr int CBINS = 1 << CBITS;      // >= N -> single chunk pass

// ------------------------------------------------- LDS-privatized histogram
// grid (P, chunks, 2): arr 0 = row (out-degree), arr 1 = col (in-count).
// 4-bit packed bins: per-(slice,chunk,node) counts <= ~5 << 15 (lambda=0.125).
__global__ void k_hist(const int* __restrict__ ei, int E, int N, int sliceLen,
                       unsigned char* __restrict__ partialR,
                       unsigned char* __restrict__ partialC, int NN) {
    __shared__ unsigned int lh[CBINS / 8];
    const int p = blockIdx.x, chunk = blockIdx.y, arr = blockIdx.z;
    const int lo = chunk << CBITS;
    const int hi = min(lo + CBINS, N);
    for (int t = threadIdx.x; t < CBINS / 8; t += TPBW) lh[t] = 0;
    __syncthreads();
    const int* idx = ei + (size_t)arr * E;
    const int s = p * sliceLen, send = min(s + sliceLen, E);
    for (int e = s + threadIdx.x; e < send; e += TPBW) {
        int v = idx[e];
        if (v >= lo && v < hi) {
            int b = v - lo;
            atomicAdd(&lh[b >> 3], 1u << ((b & 7) * 4));
        }
    }
    __syncthreads();
    // unpack nibbles -> u8 partials (8 nodes per LDS word -> uint2 store)
    unsigned char* outp = (arr == 0 ? partialR : partialC) + (size_t)p * NN + lo;
    const int nWords = (hi - lo + 7) >> 3;
    for (int w = threadIdx.x; w < nWords; w += TPBW) {
        unsigned int v = lh[w];
        uint2 o;
        o.x = (v & 0xFu) | (((v >> 4) & 0xFu) << 8) |
              (((v >> 8) & 0xFu) << 16) | (((v >> 12) & 0xFu) << 24);
        o.y = ((v >> 16) & 0xFu) | (((v >> 20) & 0xFu) << 8) |
              (((v >> 24) & 0xFu) << 16) | (((v >> 28) & 0xFu) << 24);
        *(uint2*)(outp + 8 * w) = o;
    }
}

// --------------------------------- reduce partials + fused block sums (x4 vec)
// 4 nodes/thread via packed-u32 byte lanes (per-node totals <= ~66, no carry).
__global__ void k_reduce(const unsigned char* __restrict__ partialR,
                         unsigned char* __restrict__ partialC,
                         int NN, int P,
                         float* __restrict__ dis, int* __restrict__ cnt,
                         int* __restrict__ bsum) {
    __shared__ int s[256];
    const int t = threadIdx.x;
    const int i0 = blockIdx.x * 1024 + t * 4;
    int local = 0;
    if (i0 < NN) {
        const size_t strideU = (size_t)NN >> 2;
        const unsigned int* pr = (const unsigned int*)(partialR + i0);
        unsigned int* pc = (unsigned int*)(partialC + i0);
        unsigned int degp = 0, runp = 0;
        for (int p = 0; p < P; p++) {
            degp += *pr; pr += strideU;
            unsigned int v = *pc;
            *pc = runp; runp += v;
            pc += strideU;
        }
        int d0 = degp & 255, d1 = (degp >> 8) & 255,
            d2 = (degp >> 16) & 255, d3 = degp >> 24;
        float4 dv;
        dv.x = d0 ? rsqrtf((float)d0) : 0.0f;
        dv.y = d1 ? rsqrtf((float)d1) : 0.0f;
        dv.z = d2 ? rsqrtf((float)d2) : 0.0f;
        dv.w = d3 ? rsqrtf((float)d3) : 0.0f;
        *(float4*)(dis + i0) = dv;
        int4 cv;
        cv.x = runp & 255; cv.y = (runp >> 8) & 255;
        cv.z = (runp >> 16) & 255; cv.w = runp >> 24;
        *(int4*)(cnt + i0) = cv;
        local = cv.x + cv.y + cv.z + cv.w;
    }
    s[t] = local;
    __syncthreads();
    for (int off = 128; off > 0; off >>= 1) {
        if (t < off) s[t] += s[t + off];
        __syncthreads();
    }
    if (t == 0) bsum[blockIdx.x] = s[0];
}

// in-place exclusive scan of bsum[0..NB), single block, chunked
__global__ void k_scan2(int* __restrict__ bsum, int NB) {
    __shared__ int tmp[2][256];
    __shared__ int carry_s;
    int t = threadIdx.x;
    if (t == 0) carry_s = 0;
    __syncthreads();
    for (int chunk = 0; chunk < NB; chunk += 256) {
        int idx = chunk + t;
        int v = (idx < NB) ? bsum[idx] : 0;
        int buf = 0;
        tmp[0][t] = v;
        __syncthreads();
        for (int off = 1; off < 256; off <<= 1) {
            int nv = tmp[buf][t] + ((t >= off) ? tmp[buf][t - off] : 0);
            buf ^= 1;
            tmp[buf][t] = nv;
            __syncthreads();
        }
        int incl = tmp[buf][t];
        int carry = carry_s;
        if (idx < NB) bsum[idx] = carry + incl - v;
        __syncthreads();
        if (t == 255) carry_s = carry + incl;
        __syncthreads();
    }
}

// base = global exclusive prefix of cnt; 4 nodes/thread, 1024-node blocks
__global__ void k_scan3(const int* __restrict__ cnt, const int* __restrict__ bsum,
                        int* __restrict__ base, int NN) {
    __shared__ int tmp[2][256];
    const int t = threadIdx.x;
    const int i0 = blockIdx.x * 1024 + t * 4;
    int4 c = make_int4(0, 0, 0, 0);
    if (i0 < NN) c = *(const int4*)(cnt + i0);
    int sum = c.x + c.y + c.z + c.w;
    int buf = 0;
    tmp[0][t] = sum;
    __syncthreads();
    for (int off = 1; off < 256; off <<= 1) {
        int nv = tmp[buf][t] + ((t >= off) ? tmp[buf][t - off] : 0);
        buf ^= 1;
        tmp[buf][t] = nv;
        __syncthreads();
    }
    int pre = tmp[buf][t] - sum + bsum[blockIdx.x];
    if (i0 < NN) {
        int4 b;
        b.x = pre;
        b.y = pre + c.x;
        b.z = b.y + c.y;
        b.w = b.z + c.z;
        *(int4*)(base + i0) = b;
    }
}

// ------------------------------------------- CSR scatter, NO global atomics
// pos = base[c] + offC[p][c] + LDS-local rank (4-bit packed counters)
__global__ void k_scatter(const int* __restrict__ ei, const float* __restrict__ ea,
                          const float* __restrict__ dis,
                          const int* __restrict__ base,
                          const unsigned char* __restrict__ offC,
                          int4* __restrict__ rec, int E, int N, int NN, int sliceLen) {
    __shared__ unsigned int lc[CBINS / 8];
    const int p = blockIdx.x, chunk = blockIdx.y;
    const int lo = chunk << CBITS;
    const int hi = min(lo + CBINS, N);
    for (int t = threadIdx.x; t < CBINS / 8; t += TPBW) lc[t] = 0;
    __syncthreads();
    const int* colA = ei + E;
    const unsigned char* offp = offC + (size_t)p * NN;
    const int s = p * sliceLen, send = min(s + sliceLen, E);
    for (int e = s + threadIdx.x; e < send; e += TPBW) {
        int c = colA[e];
        if (c < lo || c >= hi) continue;
        int b = c - lo;
        const int sh = (b & 7) * 4;
        unsigned int old = atomicAdd(&lc[b >> 3], 1u << sh);
        int rank = (int)((old >> sh) & 0xFu);
        int r = ei[e];
        float nrm = dis[r] * dis[c];
        float2 ev = ((const float2*)ea)[e];
        int pos = base[c] + (int)offp[c] + rank;
        int4 rv;
        rv.x = r;
        rv.y = __float_as_int(nrm);
        rv.z = __float_as_int(nrm * ev.x);
        rv.w = __float_as_int(nrm * ev.y);
        rec[pos] = rv;
    }
}

// ------------------------------------------- gather L1 + node update (fused)
__global__ void k_gather1(const float* __restrict__ x, const int4* __restrict__ rec,
                          const int* __restrict__ base, const int* __restrict__ cnt,
                          const float* __restrict__ Wc, const float* __restrict__ bc,
                          const float* __restrict__ Wn,
                          float* __restrict__ h, int N) {
    __shared__ float sWc[3 * 16], sbc[16], sWn[5 * 16];
    for (int t = threadIdx.x; t < 48; t += blockDim.x) sWc[t] = Wc[t];
    for (int t = threadIdx.x; t < 16; t += blockDim.x) sbc[t] = bc[t];
    for (int t = threadIdx.x; t < 80; t += blockDim.x) sWn[t] = Wn[t];
    __syncthreads();
    int i = blockIdx.x * blockDim.x + threadIdx.x;
    if (i >= N) return;
    int b0 = base[i], dg = cnt[i];
    float a0 = 0, a1 = 0, a2 = 0, a3 = 0, a4 = 0;
    for (int k = 0; k < dg; k++) {
        int4 rv = rec[b0 + k];
        float nrm = __int_as_float(rv.y);
        const float* xr = x + 3 * (long)rv.x;
        a0 += nrm * xr[0];
        a1 += nrm * xr[1];
        a2 += nrm * xr[2];
        a3 += __int_as_float(rv.z);
        a4 += __int_as_float(rv.w);
    }
    float inv = 1.0f / fmaxf((float)dg, 1.0f);
    float m[5] = {a0 * inv, a1 * inv, a2 * inv, a3 * inv, a4 * inv};
    float xv[3];
#pragma unroll
    for (int j = 0; j < 3; j++) xv[j] = x[3 * (long)i + j];
    float o[16];
#pragma unroll
    for (int k = 0; k < 16; k++) {
        float v = sbc[k];
#pragma unroll
        for (int j = 0; j < 3; j++) v += xv[j] * sWc[j * 16 + k];
#pragma unroll
        for (int j = 0; j < 5; j++) v += m[j] * sWn[j * 16 + k];
        o[k] = fmaxf(v, 0.0f);
    }
    float4* hp = (float4*)(h + 16 * (long)i);
#pragma unroll
    for (int q = 0; q < 4; q++)
        hp[q] = make_float4(o[4 * q], o[4 * q + 1], o[4 * q + 2], o[4 * q + 3]);
}

// ------------------------------- gather L2 + node update + pooling (fused)
__global__ void k_gather2(const float* __restrict__ h, const int4* __restrict__ rec,
                          const int* __restrict__ base, const int* __restrict__ cnt,
                          const int* __restrict__ batch,
                          const float* __restrict__ Wc, const float* __restrict__ bc,
                          const float* __restrict__ Wn,
                          float* __restrict__ pool, int* __restrict__ poolcnt, int N) {
    __shared__ float sWc[16 * 16], sbc[16], sWn[18 * 16];
    __shared__ float sp[64 * 16];
    __shared__ int   sc[64];
    for (int t = threadIdx.x; t < 256; t += blockDim.x) sWc[t] = Wc[t];
    for (int t = threadIdx.x; t < 16;  t += blockDim.x) sbc[t] = bc[t];
    for (int t = threadIdx.x; t < 288; t += blockDim.x) sWn[t] = Wn[t];
    for (int t = threadIdx.x; t < 1024; t += blockDim.x) sp[t] = 0.0f;
    for (int t = threadIdx.x; t < 64;  t += blockDim.x) sc[t] = 0;
    __syncthreads();
    int i = blockIdx.x * blockDim.x + threadIdx.x;
    if (i < N) {
        int b0 = base[i], dg = cnt[i];
        float m[18];
#pragma unroll
        for (int j = 0; j < 18; j++) m[j] = 0.0f;
        for (int k = 0; k < dg; k++) {
            int4 rv = rec[b0 + k];
            float nrm = __int_as_float(rv.y);
            const float4* hr = (const float4*)(h + 16 * (long)rv.x);
            float4 h0 = hr[0], h1 = hr[1], h2 = hr[2], h3 = hr[3];
            m[0]  += nrm * h0.x;  m[1]  += nrm * h0.y;
            m[2]  += nrm * h0.z;  m[3]  += nrm * h0.w;
            m[4]  += nrm * h1.x;  m[5]  += nrm * h1.y;
            m[6]  += nrm * h1.z;  m[7]  += nrm * h1.w;
            m[8]  += nrm * h2.x;  m[9]  += nrm * h2.y;
            m[10] += nrm * h2.z;  m[11] += nrm * h2.w;
            m[12] += nrm * h3.x;  m[13] += nrm * h3.y;
            m[14] += nrm * h3.z;  m[15] += nrm * h3.w;
            m[16] += __int_as_float(rv.z);
            m[17] += __int_as_float(rv.w);
        }
        float inv = 1.0f / fmaxf((float)dg, 1.0f);
#pragma unroll
        for (int j = 0; j < 18; j++) m[j] *= inv;
        float hv[16];
        const float4* hp = (const float4*)(h + 16 * (long)i);
#pragma unroll
        for (int q = 0; q < 4; q++) {
            float4 t4 = hp[q];
            hv[4 * q] = t4.x; hv[4 * q + 1] = t4.y;
            hv[4 * q + 2] = t4.z; hv[4 * q + 3] = t4.w;
        }
        int b = batch[i];
        atomicAdd(&sc[b], 1);
#pragma unroll
        for (int k = 0; k < 16; k++) {
            float v = sbc[k];
#pragma unroll
            for (int j = 0; j < 16; j++) v += hv[j] * sWc[j * 16 + k];
#pragma unroll
            for (int j = 0; j < 18; j++) v += m[j] * sWn[j * 16 + k];
            v = fmaxf(v, 0.0f);
            unsafeAtomicAdd(&sp[b * 16 + k], v);
        }
    }
    __syncthreads();
    for (int t = threadIdx.x; t < 1024; t += blockDim.x)
        if (sp[t] != 0.0f) unsafeAtomicAdd(&pool[t], sp[t]);
    for (int t = threadIdx.x; t < 64; t += blockDim.x)
        if (sc[t]) atomicAdd(&poolcnt[t], sc[t]);
}

// ---------------------------------------------------------------- MLP head
__global__ void k_final(const float* __restrict__ pool, const int* __restrict__ poolcnt,
                        const float* __restrict__ Wl1, const float* __restrict__ bl1,
                        const float* __restrict__ Wl2, const float* __restrict__ bl2,
                        float* __restrict__ out) {
    int g = threadIdx.x;
    if (g >= 64) return;
    float inv = 1.0f / fmaxf((float)poolcnt[g], 1.0f);
    float gv[16];
#pragma unroll
    for (int k = 0; k < 16; k++) gv[k] = pool[g * 16 + k] * inv;
    float t[16];
#pragma unroll
    for (int k = 0; k < 16; k++) {
        float v = bl1[k];
#pragma unroll
        for (int j = 0; j < 16; j++) v += gv[j] * Wl1[j * 16 + k];
        t[k] = fmaxf(v, 0.0f);
    }
    float o0 = bl2[0], o1 = bl2[1];
#pragma unroll
    for (int j = 0; j < 16; j++) {
        o0 += t[j] * Wl2[j * 2 + 0];
        o1 += t[j] * Wl2[j * 2 + 1];
    }
    out[2 * g + 0] = o0;
    out[2 * g + 1] = o1;
}

extern "C" void kernel_launch(void* const* d_in, const int* in_sizes, int n_in,
                              void* d_out, int out_size, void* d_ws, size_t ws_size,
                              hipStream_t stream) {
    const float* x     = (const float*)d_in[0];
    const int*   ei    = (const int*)  d_in[1];
    const float* ea    = (const float*)d_in[2];
    const int*   batch = (const int*)  d_in[3];
    const float* Wc1   = (const float*)d_in[4];
    const float* bc1   = (const float*)d_in[5];
    const float* Wn1   = (const float*)d_in[6];
    const float* Wc2   = (const float*)d_in[7];
    const float* bc2   = (const float*)d_in[8];
    const float* Wn2   = (const float*)d_in[9];
    const float* Wl1   = (const float*)d_in[10];
    const float* bl1   = (const float*)d_in[11];
    const float* Wl2   = (const float*)d_in[12];
    const float* bl2   = (const float*)d_in[13];
    float* out = (float*)d_out;

    const int N  = in_sizes[0] / 3;
    const int E  = in_sizes[1] / 2;
    const int NN = (N + 7) & ~7;                  // u8 arrays padded to 8 (uint2 writeout)
    const int NBR = (NN + 1023) / 1024;           // 1024-node blocks for reduce/scan
    const int chunks = (N + CBINS - 1) >> CBITS;  // == 1 for N <= 131072

    // workspace accounting; shrink P if tight
    auto wsNeeded = [&](int P) -> size_t {
        size_t s = 0;
        s += 4352 + 256;                                   // pool+poolcnt
        s += 3 * (((size_t)NN * 4 + 255) & ~(size_t)255);  // dis,cnt,base
        s += ((size_t)NBR * 4 + 255) & ~(size_t)255;       // bsum
        s += ((size_t)P * NN + 255) & ~(size_t)255;        // offC (u8)
        size_t trans = (size_t)P * NN;                     // partialR (u8)
        size_t recb  = (size_t)E * 16;                     // rec
        s += ((trans > recb ? trans : recb) + 255) & ~(size_t)255;
        s += (size_t)N * 16 * 4;                           // h
        return s + 4096;
    };
    int P = 256;
    while (P > 16 && wsNeeded(P) > ws_size) P >>= 1;
    const int sliceLen = (E + P - 1) / P;

    char* ws = (char*)d_ws;
    size_t o = 0;
    auto alloc = [&](size_t bytes) {
        void* p = ws + o;
        o += (bytes + 255) & ~(size_t)255;
        return p;
    };
    // zeroed region (pool + poolcnt only)
    float* pool    = (float*)alloc(64 * 16 * 4);
    int*   poolcnt = (int*)  alloc(64 * 4);
    size_t zbytes = o;
    // non-zeroed (fully overwritten before read)
    float* dis  = (float*)alloc((size_t)NN * 4);
    int*   cnt  = (int*)  alloc((size_t)NN * 4);
    int*   base = (int*)  alloc((size_t)NN * 4);
    int*   bsum = (int*)  alloc((size_t)NBR * 4);
    unsigned char* offC = (unsigned char*)alloc((size_t)P * NN);
    // overlay: partialR (dead after k_reduce) shares space with rec
    size_t ovStart = o;
    unsigned char* partialR = (unsigned char*)(ws + ovStart);
    size_t trans = (size_t)P * NN, recb = (size_t)E * 16;
    int4*  rec = (int4*)(ws + ovStart);
    o = ovStart + (((trans > recb ? trans : recb) + 255) & ~(size_t)255);
    float* h = (float*)alloc((size_t)N * 16 * 4);
    (void)ws_size;

    hipMemsetAsync(d_ws, 0, zbytes, stream);

    int gN = (N + TPB - 1) / TPB;
    k_hist   <<<dim3(P, chunks, 2), TPBW, 0, stream>>>(ei, E, N, sliceLen,
                                                       partialR, offC, NN);
    k_reduce <<<NBR, 256, 0, stream>>>(partialR, offC, NN, P, dis, cnt, bsum);
    k_scan2  <<<1, 256, 0, stream>>>(bsum, NBR);
    k_scan3  <<<NBR, 256, 0, stream>>>(cnt, bsum, base, NN);
    k_scatter<<<dim3(P, chunks), TPBW, 0, stream>>>(ei, ea, dis, base, offC, rec,
                                                    E, N, NN, sliceLen);
    k_gather1<<<gN, TPB, 0, stream>>>(x, rec, base, cnt, Wc1, bc1, Wn1, h, N);
    k_gather2<<<gN, TPB, 0, stream>>>(h, rec, base, cnt, batch, Wc2, bc2, Wn2,
                                      pool, poolcnt, N);
    k_final  <<<1, 64, 0, stream>>>(pool, poolcnt, Wl1, bl1, Wl2, bl2, out);
}

// Round 8
// 427.449 us; speedup vs baseline: 1.1627x; 1.1627x over previous
//
#include <hip/hip_runtime.h>

constexpr int TPB  = 256;
constexpr int TPBW = 1024;
constexpr int P     = 256;             // edge slices
constexpr int BSH   = 8;               // 256 nodes per bucket
constexpr int CBITS = 17;              // nibble row-hist bins (covers N<=131072)
constexpr int CBINS = 1 << CBITS;

// ---------------------------------------------- per-slice bucket counts (cols)
__global__ void k_prep(const int* __restrict__ col, int E, int sliceLen,
                       int* __restrict__ cntTab, int NBKT) {
    __shared__ int cl[512];
    const int p = blockIdx.x;
    for (int t = threadIdx.x; t < NBKT; t += TPBW) cl[t] = 0;
    __syncthreads();
    const int s = p * sliceLen, send = min(s + sliceLen, E);
    for (int e = s + threadIdx.x; e < send; e += TPBW)
        atomicAdd(&cl[col[e] >> BSH], 1);
    __syncthreads();
    for (int b = threadIdx.x; b < NBKT; b += TPBW) cntTab[b * P + p] = cl[b];
}

// ---------------------------------------------- nibble row histogram (degree)
__global__ void k_histrow(const int* __restrict__ row, int E, int sliceLen,
                          unsigned int* __restrict__ partialR, int W) {
    __shared__ unsigned int lh[CBINS / 8];
    const int p = blockIdx.x;
    for (int t = threadIdx.x; t < CBINS / 8; t += TPBW) lh[t] = 0;
    __syncthreads();
    const int s = p * sliceLen, send = min(s + sliceLen, E);
    for (int e = s + threadIdx.x; e < send; e += TPBW) {
        int v = row[e];
        atomicAdd(&lh[v >> 3], 1u << ((v & 7) * 4));
    }
    __syncthreads();
    for (int w = threadIdx.x; w < W; w += TPBW)
        partialR[(size_t)p * W + w] = lh[w];
}

// ---------------------------------------------- hierarchical scan of cntTab
__global__ void k_scanB1(int* __restrict__ tab, int total, int* __restrict__ bs) {
    __shared__ int tmp[2][1024];
    const int t = threadIdx.x, idx = blockIdx.x * 1024 + t;
    int v = (idx < total) ? tab[idx] : 0;
    int buf = 0;
    tmp[0][t] = v;
    __syncthreads();
    for (int off = 1; off < 1024; off <<= 1) {
        int nv = tmp[buf][t] + ((t >= off) ? tmp[buf][t - off] : 0);
        buf ^= 1; tmp[buf][t] = nv;
        __syncthreads();
    }
    int incl = tmp[buf][t];
    if (idx < total) tab[idx] = incl - v;     // block-local exclusive
    if (t == 1023) bs[blockIdx.x] = incl;
}

__global__ void k_scan2(int* __restrict__ bsum, int NB) {
    __shared__ int tmp[2][256];
    __shared__ int carry_s;
    int t = threadIdx.x;
    if (t == 0) carry_s = 0;
    __syncthreads();
    for (int chunk = 0; chunk < NB; chunk += 256) {
        int idx = chunk + t;
        int v = (idx < NB) ? bsum[idx] : 0;
        int buf = 0;
        tmp[0][t] = v;
        __syncthreads();
        for (int off = 1; off < 256; off <<= 1) {
            int nv = tmp[buf][t] + ((t >= off) ? tmp[buf][t - off] : 0);
            buf ^= 1; tmp[buf][t] = nv;
            __syncthreads();
        }
        int incl = tmp[buf][t];
        int carry = carry_s;
        if (idx < NB) bsum[idx] = carry + incl - v;
        __syncthreads();
        if (t == 255) carry_s = carry + incl;
        __syncthreads();
    }
}

__global__ void k_scanB3(int* __restrict__ tab, int total, const int* __restrict__ bs,
                         int* __restrict__ segBase, int NBKT, int E) {
    const int idx = blockIdx.x * 1024 + threadIdx.x;
    if (idx < total) {
        int v = tab[idx] + bs[blockIdx.x];
        tab[idx] = v;
        if ((idx & (P - 1)) == 0) segBase[idx / P] = v;
    }
    if (idx == 0) segBase[NBKT] = E;
}

// ---------------------------------------------- reduce row partials -> dis
__global__ void k_disr(const unsigned int* __restrict__ partialR, int W, int N,
                       float* __restrict__ dis) {
    const int w = blockIdx.x * blockDim.x + threadIdx.x;
    if (w >= W) return;
    const unsigned int* pr = partialR + w;
    unsigned int accA = 0, accB = 0;            // byte lanes, totals <= ~66
    for (int p = 0; p < P; p++) {
        unsigned int v = pr[(size_t)p * W];
        accA += v & 0x0F0F0F0Fu;
        accB += (v >> 4) & 0x0F0F0F0Fu;
    }
    int d[8];
    d[0] = accA & 255; d[2] = (accA >> 8) & 255;
    d[4] = (accA >> 16) & 255; d[6] = accA >> 24;
    d[1] = accB & 255; d[3] = (accB >> 8) & 255;
    d[5] = (accB >> 16) & 255; d[7] = accB >> 24;
    const int n0 = w * 8;
    if (n0 + 7 < N) {
        float4 v0, v1;
        v0.x = d[0] ? rsqrtf((float)d[0]) : 0.f;
        v0.y = d[1] ? rsqrtf((float)d[1]) : 0.f;
        v0.z = d[2] ? rsqrtf((float)d[2]) : 0.f;
        v0.w = d[3] ? rsqrtf((float)d[3]) : 0.f;
        v1.x = d[4] ? rsqrtf((float)d[4]) : 0.f;
        v1.y = d[5] ? rsqrtf((float)d[5]) : 0.f;
        v1.z = d[6] ? rsqrtf((float)d[6]) : 0.f;
        v1.w = d[7] ? rsqrtf((float)d[7]) : 0.f;
        *(float4*)(dis + n0) = v0;
        *(float4*)(dis + n0 + 4) = v1;
    } else {
#pragma unroll
        for (int k = 0; k < 8; k++)
            if (n0 + k < N) dis[n0 + k] = d[k] ? rsqrtf((float)d[k]) : 0.f;
    }
}

// ---------------------------------------------- stage into bucket-major runs
__global__ void k_stage(const int* __restrict__ ei, const float2* __restrict__ ea,
                        int E, int sliceLen, const int* __restrict__ cntTab,
                        int NBKT, int4* __restrict__ staged) {
    __shared__ int lb[512];
    const int p = blockIdx.x;
    for (int t = threadIdx.x; t < NBKT; t += TPBW) lb[t] = 0;
    __syncthreads();
    const int* colA = ei + E;
    const int s = p * sliceLen, send = min(s + sliceLen, E);
    for (int e = s + threadIdx.x; e < send; e += TPBW) {
        int c = colA[e];
        int b = c >> BSH;
        int pos = cntTab[b * P + p] + atomicAdd(&lb[b], 1);
        float2 ev = ea[e];
        staged[pos] = make_int4(ei[e], c, __float_as_int(ev.x), __float_as_int(ev.y));
    }
}

// ------------------------- per-bucket counting sort + layer-1 edge sums
// writes rec8={row,nrm}, base, cnt, acc1[node][5] = {S nrm*x0..2, S nrm*ea}
__global__ void k_sort(const int4* __restrict__ staged, const int* __restrict__ segBase,
                       const float* __restrict__ dis, const float* __restrict__ x,
                       int N, int2* __restrict__ rec, int* __restrict__ base,
                       int* __restrict__ cnt, float* __restrict__ acc1) {
    __shared__ int lcnt[256], lexc[256], lfill[256];
    __shared__ int sc0[2][256];
    __shared__ float lac[256 * 5];
    const int b = blockIdx.x, t = threadIdx.x;
    const int s0 = segBase[b], s1 = segBase[b + 1], c0 = b << BSH;
    if (t < 256) { lcnt[t] = 0; lfill[t] = 0; }
    for (int k = t; k < 1280; k += TPBW) lac[k] = 0.f;
    __syncthreads();
    for (int e = s0 + t; e < s1; e += TPBW)
        atomicAdd(&lcnt[staged[e].y & 255], 1);
    __syncthreads();
    if (t < 256) sc0[0][t] = lcnt[t];
    __syncthreads();
    int buf = 0;
    for (int off = 1; off < 256; off <<= 1) {
        if (t < 256) {
            int nv = sc0[buf][t] + ((t >= off) ? sc0[buf][t - off] : 0);
            sc0[buf ^ 1][t] = nv;
        }
        __syncthreads();
        buf ^= 1;
    }
    if (t < 256) {
        int incl = sc0[buf][t];
        int ex = incl - lcnt[t];
        lexc[t] = ex;
        int node = c0 + t;
        if (node < N) { base[node] = s0 + ex; cnt[node] = lcnt[t]; }
    }
    __syncthreads();
    for (int e = s0 + t; e < s1; e += TPBW) {
        int4 rv = staged[e];
        int c = rv.y, j = c & 255;
        float nrm = dis[rv.x] * dis[c];
        int rank = atomicAdd(&lfill[j], 1);
        rec[s0 + lexc[j] + rank] = make_int2(rv.x, __float_as_int(nrm));
        const float* xr = x + 3 * (long)rv.x;
        unsafeAtomicAdd(&lac[j * 5 + 0], nrm * xr[0]);
        unsafeAtomicAdd(&lac[j * 5 + 1], nrm * xr[1]);
        unsafeAtomicAdd(&lac[j * 5 + 2], nrm * xr[2]);
        unsafeAtomicAdd(&lac[j * 5 + 3], nrm * __int_as_float(rv.z));
        unsafeAtomicAdd(&lac[j * 5 + 4], nrm * __int_as_float(rv.w));
    }
    __syncthreads();
    const int nb = min(256, N - c0);
    for (int k = t; k < nb * 5; k += TPBW) acc1[(size_t)c0 * 5 + k] = lac[k];
}

// ---------------------------------------------- layer-1 node update (no edges)
__global__ void k_node1(const float* __restrict__ x, const float* __restrict__ acc,
                        const int* __restrict__ cnt,
                        const float* __restrict__ Wc, const float* __restrict__ bc,
                        const float* __restrict__ Wn,
                        float* __restrict__ h, int N) {
    __shared__ float sWc[3 * 16], sbc[16], sWn[5 * 16];
    for (int t = threadIdx.x; t < 48; t += blockDim.x) sWc[t] = Wc[t];
    for (int t = threadIdx.x; t < 16; t += blockDim.x) sbc[t] = bc[t];
    for (int t = threadIdx.x; t < 80; t += blockDim.x) sWn[t] = Wn[t];
    __syncthreads();
    int i = blockIdx.x * blockDim.x + threadIdx.x;
    if (i >= N) return;
    float inv = 1.0f / fmaxf((float)cnt[i], 1.0f);
    float m[5];
#pragma unroll
    for (int j = 0; j < 5; j++) m[j] = acc[(size_t)i * 5 + j] * inv;
    float xv[3];
#pragma unroll
    for (int j = 0; j < 3; j++) xv[j] = x[3 * (long)i + j];
    float o[16];
#pragma unroll
    for (int k = 0; k < 16; k++) {
        float v = sbc[k];
#pragma unroll
        for (int j = 0; j < 3; j++) v += xv[j] * sWc[j * 16 + k];
#pragma unroll
        for (int j = 0; j < 5; j++) v += m[j] * sWn[j * 16 + k];
        o[k] = fmaxf(v, 0.0f);
    }
    float4* hp = (float4*)(h + 16 * (long)i);
#pragma unroll
    for (int q = 0; q < 4; q++)
        hp[q] = make_float4(o[4 * q], o[4 * q + 1], o[4 * q + 2], o[4 * q + 3]);
}

// ------------------------------- gather L2 + node update + pooling (fused)
__global__ void k_gather2(const float* __restrict__ h, const int2* __restrict__ rec,
                          const int* __restrict__ base, const int* __restrict__ cnt,
                          const float* __restrict__ acc, const int* __restrict__ batch,
                          const float* __restrict__ Wc, const float* __restrict__ bc,
                          const float* __restrict__ Wn,
                          float* __restrict__ pool, int* __restrict__ poolcnt, int N) {
    __shared__ float sWc[16 * 16], sbc[16], sWn[18 * 16];
    __shared__ float sp[64 * 16];
    __shared__ int   sc[64];
    for (int t = threadIdx.x; t < 256; t += blockDim.x) sWc[t] = Wc[t];
    for (int t = threadIdx.x; t < 16;  t += blockDim.x) sbc[t] = bc[t];
    for (int t = threadIdx.x; t < 288; t += blockDim.x) sWn[t] = Wn[t];
    for (int t = threadIdx.x; t < 1024; t += blockDim.x) sp[t] = 0.0f;
    for (int t = threadIdx.x; t < 64;  t += blockDim.x) sc[t] = 0;
    __syncthreads();
    int i = blockIdx.x * blockDim.x + threadIdx.x;
    if (i < N) {
        int b0 = base[i], dg = cnt[i];
        float m[18];
#pragma unroll
        for (int j = 0; j < 16; j++) m[j] = 0.0f;
        for (int k = 0; k < dg; k++) {
            int2 rv = rec[b0 + k];
            float nrm = __int_as_float(rv.y);
            const float4* hr = (const float4*)(h + 16 * (long)rv.x);
            float4 h0 = hr[0], h1 = hr[1], h2 = hr[2], h3 = hr[3];
            m[0]  += nrm * h0.x;  m[1]  += nrm * h0.y;
            m[2]  += nrm * h0.z;  m[3]  += nrm * h0.w;
            m[4]  += nrm * h1.x;  m[5]  += nrm * h1.y;
            m[6]  += nrm * h1.z;  m[7]  += nrm * h1.w;
            m[8]  += nrm * h2.x;  m[9]  += nrm * h2.y;
            m[10] += nrm * h2.z;  m[11] += nrm * h2.w;
            m[12] += nrm * h3.x;  m[13] += nrm * h3.y;
            m[14] += nrm * h3.z;  m[15] += nrm * h3.w;
        }
        m[16] = acc[(size_t)i * 5 + 3];     // shared edge-attr sums (same both layers)
        m[17] = acc[(size_t)i * 5 + 4];
        float inv = 1.0f / fmaxf((float)dg, 1.0f);
#pragma unroll
        for (int j = 0; j < 18; j++) m[j] *= inv;
        float hv[16];
        const float4* hp = (const float4*)(h + 16 * (long)i);
#pragma unroll
        for (int q = 0; q < 4; q++) {
            float4 t4 = hp[q];
            hv[4 * q] = t4.x; hv[4 * q + 1] = t4.y;
            hv[4 * q + 2] = t4.z; hv[4 * q + 3] = t4.w;
        }
        int b = batch[i];
        atomicAdd(&sc[b], 1);
#pragma unroll
        for (int k = 0; k < 16; k++) {
            float v = sbc[k];
#pragma unroll
            for (int j = 0; j < 16; j++) v += hv[j] * sWc[j * 16 + k];
#pragma unroll
            for (int j = 0; j < 18; j++) v += m[j] * sWn[j * 16 + k];
            v = fmaxf(v, 0.0f);
            unsafeAtomicAdd(&sp[b * 16 + k], v);
        }
    }
    __syncthreads();
    for (int t = threadIdx.x; t < 1024; t += blockDim.x)
        if (sp[t] != 0.0f) unsafeAtomicAdd(&pool[t], sp[t]);
    for (int t = threadIdx.x; t < 64; t += blockDim.x)
        if (sc[t]) atomicAdd(&poolcnt[t], sc[t]);
}

// ---------------------------------------------------------------- MLP head
__global__ void k_final(const float* __restrict__ pool, const int* __restrict__ poolcnt,
                        const float* __restrict__ Wl1, const float* __restrict__ bl1,
                        const float* __restrict__ Wl2, const float* __restrict__ bl2,
                        float* __restrict__ out) {
    int g = threadIdx.x;
    if (g >= 64) return;
    float inv = 1.0f / fmaxf((float)poolcnt[g], 1.0f);
    float gv[16];
#pragma unroll
    for (int k = 0; k < 16; k++) gv[k] = pool[g * 16 + k] * inv;
    float t[16];
#pragma unroll
    for (int k = 0; k < 16; k++) {
        float v = bl1[k];
#pragma unroll
        for (int j = 0; j < 16; j++) v += gv[j] * Wl1[j * 16 + k];
        t[k] = fmaxf(v, 0.0f);
    }
    float o0 = bl2[0], o1 = bl2[1];
#pragma unroll
    for (int j = 0; j < 16; j++) {
        o0 += t[j] * Wl2[j * 2 + 0];
        o1 += t[j] * Wl2[j * 2 + 1];
    }
    out[2 * g + 0] = o0;
    out[2 * g + 1] = o1;
}

extern "C" void kernel_launch(void* const* d_in, const int* in_sizes, int n_in,
                              void* d_out, int out_size, void* d_ws, size_t ws_size,
                              hipStream_t stream) {
    const float* x     = (const float*)d_in[0];
    const int*   ei    = (const int*)  d_in[1];
    const float* ea    = (const float*)d_in[2];
    const int*   batch = (const int*)  d_in[3];
    const float* Wc1   = (const float*)d_in[4];
    const float* bc1   = (const float*)d_in[5];
    const float* Wn1   = (const float*)d_in[6];
    const float* Wc2   = (const float*)d_in[7];
    const float* bc2   = (const float*)d_in[8];
    const float* Wn2   = (const float*)d_in[9];
    const float* Wl1   = (const float*)d_in[10];
    const float* bl1   = (const float*)d_in[11];
    const float* Wl2   = (const float*)d_in[12];
    const float* bl2   = (const float*)d_in[13];
    float* out = (float*)d_out;

    const int N  = in_sizes[0] / 3;
    const int E  = in_sizes[1] / 2;
    const int NBKT = (N + 255) >> BSH;            // <= 512 for N <= 131072
    const int W  = (N + 7) >> 3;                  // nibble words per row-slice
    const int total = NBKT * P;
    const int NSB = (total + 1023) / 1024;        // scan blocks over cntTab
    const int sliceLen = (E + P - 1) / P;
    const int N8 = (N + 7) & ~7;

    char* ws = (char*)d_ws;
    size_t o = 0;
    auto alloc = [&](size_t bytes) {
        void* p = ws + o;
        o += (bytes + 255) & ~(size_t)255;
        return p;
    };
    // zeroed region (pool + poolcnt only)
    float* pool    = (float*)alloc(64 * 16 * 4);
    int*   poolcnt = (int*)  alloc(64 * 4);
    size_t zbytes = o;
    // non-zeroed (fully overwritten before read)
    float* dis     = (float*)alloc((size_t)N8 * 4);
    int*   cnt     = (int*)  alloc((size_t)N8 * 4);
    int*   base    = (int*)  alloc((size_t)N8 * 4);
    int*   cntTab  = (int*)  alloc((size_t)total * 4);
    int*   bs      = (int*)  alloc((size_t)NSB * 4);
    int*   segBase = (int*)  alloc((size_t)(NBKT + 1) * 4);
    float* acc1    = (float*)alloc((size_t)N * 5 * 4);
    // region A: partialR [histrow..disr] -> staged [stage..sort] -> h [node1..g2]
    size_t szPR = (size_t)P * W * 4, szST = (size_t)E * 16, szH = (size_t)N * 16 * 4;
    size_t szA = szPR > szST ? szPR : szST;
    if (szH > szA) szA = szH;
    char* regionA = (char*)alloc(szA);
    unsigned int* partialR = (unsigned int*)regionA;
    int4*  staged = (int4*)regionA;
    float* h      = (float*)regionA;
    int2*  rec    = (int2*)alloc((size_t)E * 8);
    (void)ws_size;

    hipMemsetAsync(d_ws, 0, zbytes, stream);

    const int gN = (N + TPB - 1) / TPB;
    k_prep   <<<P, TPBW, 0, stream>>>(ei + E, E, sliceLen, cntTab, NBKT);
    k_histrow<<<P, TPBW, 0, stream>>>(ei, E, sliceLen, partialR, W);
    k_scanB1 <<<NSB, 1024, 0, stream>>>(cntTab, total, bs);
    k_scan2  <<<1, 256, 0, stream>>>(bs, NSB);
    k_scanB3 <<<NSB, 1024, 0, stream>>>(cntTab, total, bs, segBase, NBKT, E);
    k_disr   <<<(W + TPB - 1) / TPB, TPB, 0, stream>>>(partialR, W, N, dis);
    k_stage  <<<P, TPBW, 0, stream>>>(ei, (const float2*)ea, E, sliceLen,
                                      cntTab, NBKT, staged);
    k_sort   <<<NBKT, TPBW, 0, stream>>>(staged, segBase, dis, x, N,
                                         rec, base, cnt, acc1);
    k_node1  <<<gN, TPB, 0, stream>>>(x, acc1, cnt, Wc1, bc1, Wn1, h, N);
    k_gather2<<<gN, TPB, 0, stream>>>(h, rec, base, cnt, acc1, batch,
                                      Wc2, bc2, Wn2, pool, poolcnt, N);
    k_final  <<<1, 64, 0, stream>>>(pool, poolcnt, Wl1, bl1, Wl2, bl2, out);
}